// Round 9
// baseline (245.169 us; speedup 1.0000x reference)
//
#include <hip/hip_runtime.h>
#include <hip/hip_bf16.h>
#include <hip/hip_fp16.h>
#include <math.h>

#define NNODES 50000
#define NEDGES 800000
#define FIN 128
#define FH 256
#define NG 64
#define NC 64
#define NP 50176              // node dim padded to 196*256
#define SPLITX_ITEMS (NNODES * FIN / 4)      // 1.6M
#define SPLITX_BLOCKS ((SPLITX_ITEMS + 511) / 512)   // 3125
#define W1T_BLOCKS (FIN * 256 / 512)         // 64
#define GEMM_MB ((NNODES + 127) / 128)       // 391
#define GEMM_BLKS (GEMM_MB * 2)              // 782
#define QTR (NP / 4)                         // 12544 src slots per wt-build block

#define NBUCK 196             // dst>>8 buckets (256 nodes each)
#define BCAP 5120             // per-bucket capacity (mean 4096, sigma ~64 -> +16 sigma)
#define BIN_CHUNK 2048        // edges per bin block
#define BIN_BLOCKS ((NEDGES + BIN_CHUNK - 1) / BIN_CHUNK)   // 391
#define K1_BLOCKS (BIN_BLOCKS + SPLITX_BLOCKS + W1T_BLOCKS) // 3580

typedef unsigned short bhalf;
typedef __attribute__((ext_vector_type(8))) short bf16x8;
typedef __attribute__((ext_vector_type(8))) _Float16 f16x8;
typedef __attribute__((ext_vector_type(4))) float f32x4;
typedef __attribute__((ext_vector_type(4))) unsigned short u16x4;

__device__ inline bhalf f2bf_rn(float f) {
    unsigned int u = __float_as_uint(f);
    u += 0x7FFFu + ((u >> 16) & 1u);      // round-to-nearest-even
    return (bhalf)(u >> 16);
}
__device__ inline float2 bfpair(unsigned int u) {   // [lo16, hi16] -> two floats
    return make_float2(__uint_as_float(u << 16), __uint_as_float(u & 0xFFFF0000u));
}

// ---------------- K1 (512 thr): bin (blocks 0..390) | x->bf16 | W1 transpose ----------------

__global__ __launch_bounds__(512)
void k1_kernel(const int* __restrict__ src, const int* __restrict__ dst,
               int* __restrict__ bcur, unsigned int* __restrict__ binned,
               const float* __restrict__ x, bhalf* __restrict__ xb,
               const float* __restrict__ W1, bhalf* __restrict__ w1t) {
    int t = threadIdx.x;
    if (blockIdx.x >= BIN_BLOCKS) {
        int b = blockIdx.x - BIN_BLOCKS;
        if (b < SPLITX_BLOCKS) {
            int i = b * 512 + t;
            if (i < SPLITX_ITEMS) {
                float4 v = *reinterpret_cast<const float4*>(&x[i * 4]);
                u16x4 o = {f2bf_rn(v.x), f2bf_rn(v.y), f2bf_rn(v.z), f2bf_rn(v.w)};
                *reinterpret_cast<u16x4*>(&xb[i * 4]) = o;
            }
        } else {
            int i = (b - SPLITX_BLOCKS) * 512 + t;     // W1[K][256] -> w1t[256][K]
            int k = i >> 8, n = i & 255;
            w1t[n * FIN + k] = f2bf_rn(W1[i]);
        }
        return;
    }
    // ---- bin range: 4B entries {dlo:8 | src:16}, staged bucket-major in LDS ----
    __shared__ int hist[NBUCK];
    __shared__ int base[NBUCK];
    __shared__ int gb[NBUCK];
    __shared__ int lcur[NBUCK];
    __shared__ int scan_tmp[256];
    __shared__ unsigned int stage[BIN_CHUNK];
    __shared__ unsigned char bid[BIN_CHUNK];
    int e0 = blockIdx.x * BIN_CHUNK;
    for (int i = t; i < NBUCK; i += 512) hist[i] = 0;
    __syncthreads();
#pragma unroll
    for (int k = 0; k < BIN_CHUNK / 512; k++) {
        int e = e0 + k * 512 + t;
        if (e < NEDGES) atomicAdd(&hist[dst[e] >> 8], 1);
    }
    __syncthreads();
    int v = (t < NBUCK) ? hist[t] : 0;
    if (t < 256) scan_tmp[t] = v;
    __syncthreads();
#pragma unroll
    for (int off = 1; off < 256; off <<= 1) {
        int xx = (t >= off && t < 256) ? scan_tmp[t - off] : 0;
        __syncthreads();
        if (t < 256) scan_tmp[t] += xx;
        __syncthreads();
    }
    if (t < NBUCK) {
        int ex = scan_tmp[t] - v;                // exclusive
        base[t] = ex;
        lcur[t] = ex;
        gb[t] = (v > 0) ? atomicAdd(&bcur[t], v) : 0;   // bcur counts from 0
    }
    __syncthreads();
#pragma unroll
    for (int k = 0; k < BIN_CHUNK / 512; k++) {
        int e = e0 + k * 512 + t;
        if (e < NEDGES) {
            int s = src[e], d = dst[e];
            int b = d >> 8;
            int lp = atomicAdd(&lcur[b], 1);
            stage[lp] = (unsigned int)s | ((unsigned int)(d & 255) << 16);
            bid[lp] = (unsigned char)b;          // b < 196 fits u8
        }
    }
    __syncthreads();
    int total = base[NBUCK - 1] + hist[NBUCK - 1];
    for (int i = t; i < total; i += 512) {
        int b = bid[i];
        binned[(size_t)b * BCAP + gb[b] + (i - base[b])] = stage[i];
    }
}

// ---------------- pass 2 (512 thr): per-bucket degree+dinv+row_start+CSR placement ----------------

__global__ __launch_bounds__(512)
void place_kernel(const unsigned int* __restrict__ binned, const int* __restrict__ bcur,
                  int* __restrict__ row_start, float* __restrict__ dinv,
                  unsigned int* __restrict__ edata) {
    __shared__ unsigned int stage[BCAP];
    __shared__ int sc[256];
    __shared__ int deg[256];
    __shared__ int lex[256];
    __shared__ int lcur[256];
    __shared__ unsigned short dih[256];
    __shared__ int s_ebase, s_cnt;
    int b = blockIdx.x, t = threadIdx.x;
    // exclusive prefix over bucket counts -> global edge base of this bucket
    int c = (t < NBUCK) ? bcur[t] : 0;
    if (t < 256) sc[t] = c;
    __syncthreads();
#pragma unroll
    for (int off = 1; off < 256; off <<= 1) {
        int x = (t >= off && t < 256) ? sc[t - off] : 0;
        __syncthreads();
        if (t < 256) sc[t] += x;
        __syncthreads();
    }
    if (t == b) { s_ebase = sc[t] - c; s_cnt = c; }
    if (t < 256) deg[t] = 0;
    __syncthreads();
    int cnt = s_cnt, eb = s_ebase;
    const unsigned int* bp = &binned[(size_t)b * BCAP];
    for (int i = t; i < cnt; i += 512) stage[i] = bp[i];
    __syncthreads();
    for (int i = t; i < cnt; i += 512) atomicAdd(&deg[(stage[i] >> 16) & 255], 1);
    __syncthreads();
    int d = (t < 256) ? deg[t] : 0;
    if (t < 256) {
        float di = rsqrtf((float)d + 1.0f);
        int gn = (b << 8) + t;
        if (gn < NNODES) dinv[gn] = di;
        dih[t] = __half_as_ushort(__float2half(di));
        sc[t] = d;
    }
    __syncthreads();
#pragma unroll
    for (int off = 1; off < 256; off <<= 1) {
        int x = (t >= off && t < 256) ? sc[t - off] : 0;
        __syncthreads();
        if (t < 256) sc[t] += x;
        __syncthreads();
    }
    if (t < 256) {
        int lexv = sc[t] - d;                    // exclusive within bucket
        lex[t] = lexv;
        lcur[t] = 0;
        int gn = (b << 8) + t;
        if (gn <= NNODES) row_start[gn] = eb + lexv;  // row_start[N] = E lands here too
    }
    __syncthreads();
    for (int i = t; i < cnt; i += 512) {
        unsigned int e = stage[i];
        int dl = (e >> 16) & 255;
        int pos = eb + lex[dl] + atomicAdd(&lcur[dl], 1);
        edata[pos] = (e & 0xFFFFu) | ((unsigned int)dih[dl] << 16);
    }
}

// ---------------- CSR gather, 128 bf16 feats, factored norms, unroll-8 MLP ----------------

__global__ __launch_bounds__(256)
void gather128_kernel(const bhalf* __restrict__ xb, const unsigned int* __restrict__ edata,
                      const int* __restrict__ row_start, const float* __restrict__ dinv,
                      bhalf* __restrict__ z, int Nn) {
    int node = blockIdx.x * 4 + (threadIdx.x >> 6);
    if (node >= Nn) return;
    int lane = threadIdx.x & 63;
    int st = row_start[node];
    int cnt = row_start[node + 1] - st;
    float ax = 0.0f, ay = 0.0f;
    int j = 0;
    for (; j + 7 < cnt; j += 8) {
        unsigned int e[8];
        float2 v[8];
#pragma unroll
        for (int u = 0; u < 8; u++) e[u] = edata[st + j + u];
#pragma unroll
        for (int u = 0; u < 8; u++)
            v[u] = bfpair(*reinterpret_cast<const unsigned int*>(
                &xb[(size_t)(e[u] & 0xFFFFu) * FIN + lane * 2]));
#pragma unroll
        for (int u = 0; u < 8; u++) {
            float n = dinv[e[u] & 0xFFFFu];
            ax += v[u].x * n;
            ay += v[u].y * n;
        }
    }
    for (; j < cnt; j++) {
        unsigned int e0 = edata[st + j];
        int s0 = e0 & 0xFFFFu;
        float2 v0 = bfpair(*reinterpret_cast<const unsigned int*>(&xb[(size_t)s0 * FIN + lane * 2]));
        float n0 = dinv[s0];
        ax += v0.x * n0; ay += v0.y * n0;
    }
    float dn = dinv[node];
    float2 xv = bfpair(*reinterpret_cast<const unsigned int*>(&xb[(size_t)node * FIN + lane * 2]));
    ushort2 o = {f2bf_rn(dn * (ax + xv.x * dn)), f2bf_rn(dn * (ay + xv.y * dn))};
    *reinterpret_cast<ushort2*>(&z[(size_t)node * FIN + lane * 2]) = o;
}

// ---------------- wt build (512 thr): single f16 array ----------------

__global__ __launch_bounds__(512)
void wt_build_kernel(const unsigned int* __restrict__ edata, const int* __restrict__ row_start,
                     const int* __restrict__ batch, const float* __restrict__ dinv,
                     unsigned short* __restrict__ wt16) {
    __shared__ float acc[QTR];
    int g = blockIdx.x >> 2;
    int q = blockIdx.x & 3;
    int base = q * QTR;
    for (int i = threadIdx.x; i < QTR; i += 512) acc[i] = 0.0f;
    // node range [na, nb) of graph g (batch sorted)
    int lo = 0, hi = NNODES;
    while (lo < hi) { int m = (lo + hi) >> 1; if (batch[m] < g) lo = m + 1; else hi = m; }
    int na = lo;
    hi = NNODES;               // nb >= na since sorted
    while (lo < hi) { int m = (lo + hi) >> 1; if (batch[m] < g + 1) lo = m + 1; else hi = m; }
    int nb = lo;
    int pa = row_start[na];
    int pb = row_start[nb];
    __syncthreads();
    for (int p = pa + threadIdx.x; p < pb; p += 512) {
        unsigned int e = edata[p];
        int s = (int)(e & 0xFFFFu) - base;
        if ((unsigned int)s < (unsigned int)QTR)
            atomicAdd(&acc[s], __half2float(__ushort_as_half((unsigned short)(e >> 16))));
    }
    __syncthreads();
    size_t rowo = (size_t)g * NP + base;
    for (int i = threadIdx.x; i < QTR; i += 512) {
        int s = base + i;
        float dv = (s < NNODES) ? dinv[s] : 0.0f;
        float v = acc[i];
        if (s >= na && s < nb) v += dv;          // self-loop (becomes dinv^2)
        v *= dv;
        wt16[rowo + i] = __half_as_ushort(__float2half(v));
    }
}

// ---------------- fused GEMM + q-partial: DIRECT-LOAD phase A (no LDS staging) ----------------
// K = FIN = 128 means A/B fragments load straight from global in MFMA layout:
// lanes {l15, l15+16, l15+32, l15+48} of a wave cover 64 consecutive bytes of
// one row -> 64B-granule coalesced. Phase A has ZERO barriers and 32
// independent 16B loads the compiler pipelines with counted vmcnt (the old
// stage->barrier->compute->barrier lockstep ran at 1.2 TB/s effective with
// MfmaUtil 5%). OOB rows clamp to M-1: finite values x wt pad (=0) = 0.

__global__ __launch_bounds__(256)
void gemmq_kernel(const bhalf* __restrict__ A, const bhalf* __restrict__ Bt,
                  const float* __restrict__ bias, const unsigned short* __restrict__ wt16,
                  float* __restrict__ qpart, int M) {
    __shared__ alignas(16) bhalf h1s[128 * 136];       // only LDS: phase B->C handoff
    const int tid  = threadIdx.x;
    const int lane = tid & 63;
    const int wave = tid >> 6;
    const int quad = lane >> 4;
    const int l15  = lane & 15;
    const int wm = (wave & 1) * 64;
    const int wn = (wave >> 1) * 64;
    const int bm = (blockIdx.x >> 1) * 128;
    const int bn = (blockIdx.x & 1) * 128;

    // Phase A: acc = zb(128 nodes) @ w1t^T(128 cols), fragments direct from global.
    f32x4 acc[4][4] = {};
#pragma unroll
    for (int kt = 0; kt < 4; kt++) {
        bf16x8 af[4], bfr[4];
#pragma unroll
        for (int mi = 0; mi < 4; mi++) {
            int gm = bm + wm + mi * 16 + l15;
            if (gm >= M) gm = M - 1;             // clamp: finite garbage * wt(=0) = 0
            af[mi] = *reinterpret_cast<const bf16x8*>(&A[(size_t)gm * FIN + kt * 32 + quad * 8]);
        }
#pragma unroll
        for (int ni = 0; ni < 4; ni++)
            bfr[ni] = *reinterpret_cast<const bf16x8*>(
                &Bt[(size_t)(bn + wn + ni * 16 + l15) * FIN + kt * 32 + quad * 8]);
#pragma unroll
        for (int mi = 0; mi < 4; mi++)
#pragma unroll
            for (int ni = 0; ni < 4; ni++)
                acc[mi][ni] = __builtin_amdgcn_mfma_f32_16x16x32_bf16(af[mi], bfr[ni], acc[mi][ni], 0, 0, 0);
    }

    // prefetch phase-C wt fragments here: latency hides under phase B's erff block
    f16x8 wreg[4][4];
#pragma unroll
    for (int ki = 0; ki < 4; ki++)
#pragma unroll
        for (int gt = 0; gt < 4; gt++)
            wreg[ki][gt] = *reinterpret_cast<const f16x8*>(
                &wt16[(size_t)(gt * 16 + l15) * NP + bm + ki * 32 + quad * 8]);

    // Phase B: gelu -> f16 -> LDS h1s[col][node]
#pragma unroll
    for (int mi = 0; mi < 4; mi++) {
        int node0 = wm + mi * 16 + quad * 4;     // local node (row)
#pragma unroll
        for (int ni = 0; ni < 4; ni++) {
            int col = wn + ni * 16 + l15;        // local h-col
            float bv = bias[bn + col];
            u16x4 o;
#pragma unroll
            for (int r = 0; r < 4; r++) {
                float v = acc[mi][ni][r] + bv;
                v = 0.5f * v * (1.0f + erff(v * 0.70710678118654752f));
                o[r] = __half_as_ushort(__float2half(v));
            }
            *reinterpret_cast<u16x4*>(&h1s[col * 136 + node0]) = o;
        }
    }
    __syncthreads();

    // Phase C: q-partial. A = wt16 (rows=g, contraction=node, in regs), B = h1s.
    f32x4 qacc[4][2] = {};
    const int c0 = wave * 32;                    // this wave's 32-col slice
#pragma unroll
    for (int ki = 0; ki < 4; ki++) {
        f16x8 bfr2[2];
#pragma unroll
        for (int ct = 0; ct < 2; ct++)
            bfr2[ct] = *reinterpret_cast<const f16x8*>(&h1s[(c0 + ct * 16 + l15) * 136 + ki * 32 + quad * 8]);
#pragma unroll
        for (int gt = 0; gt < 4; gt++)
#pragma unroll
            for (int ct = 0; ct < 2; ct++)
                qacc[gt][ct] = __builtin_amdgcn_mfma_f32_16x16x32_f16(wreg[ki][gt], bfr2[ct], qacc[gt][ct], 0, 0, 0);
    }
    // store: qpart[blk][g][col]; C layout: row(g)=gt*16+quad*4+r, col=c0+ct*16+l15
    float* qp = &qpart[(size_t)blockIdx.x * NG * 128];
#pragma unroll
    for (int gt = 0; gt < 4; gt++) {
#pragma unroll
        for (int ct = 0; ct < 2; ct++) {
            int col = c0 + ct * 16 + l15;
#pragma unroll
            for (int r = 0; r < 4; r++)
                qp[(gt * 16 + quad * 4 + r) * 128 + col] = qacc[gt][ct][r];
        }
    }
}

// ---------------- qpart reduce at full chip BW: qg[g][k] = sum_blk qpart ----------------

__global__ __launch_bounds__(256)
void qreduce_kernel(const float* __restrict__ qpart, float* __restrict__ qg) {
    __shared__ float red[256];
    int g = blockIdx.x >> 2;
    int chunk = blockIdx.x & 3;
    int half = chunk >> 1;
    int col128 = (chunk & 1) * 64 + (threadIdx.x & 63);
    int mi = threadIdx.x >> 6;
    float s = 0.0f;
    for (int m = mi; m < GEMM_MB; m += 4)
        s += qpart[(size_t)(m * 2 + half) * NG * 128 + (size_t)g * 128 + col128];
    red[threadIdx.x] = s;
    __syncthreads();
    if (mi == 0) {
        int kc = threadIdx.x;
        qg[(size_t)g * FH + half * 128 + col128] =
            red[kc] + red[64 + kc] + red[128 + kc] + red[192 + kc];
    }
}

// ---------------- fused head: pooled = (qg@W2)/cnt + b2 ; out = pooled@Wfc + bfc ----------------

__global__ __launch_bounds__(256)
void p2fc_kernel(const float* __restrict__ qg, const float* __restrict__ W2,
                 const float* __restrict__ b2, const int* __restrict__ batch,
                 const float* __restrict__ Wfc, const float* __restrict__ bfc,
                 float* __restrict__ out) {
    __shared__ float qgl[FH];
    __shared__ float ps[FH];
    int g = blockIdx.x;
    int t = threadIdx.x;
    qgl[t] = qg[(size_t)g * FH + t];
    int lo = 0, hi = NNODES;
    while (lo < hi) { int m = (lo + hi) >> 1; if (batch[m] < g) lo = m + 1; else hi = m; }
    int a = lo;
    lo = 0; hi = NNODES;
    while (lo < hi) { int m = (lo + hi) >> 1; if (batch[m] < g + 1) lo = m + 1; else hi = m; }
    float inv = 1.0f / fmaxf((float)(lo - a), 1.0f);
    __syncthreads();
    float acc = 0.0f;
    for (int k = 0; k < FH; k++)
        acc += qgl[k] * W2[k * FH + t];
    ps[t] = acc * inv + b2[t];
    __syncthreads();
    if (t < NC) {
        float a2 = 0.0f;
        for (int cc = 0; cc < FH; cc++)
            a2 += ps[cc] * Wfc[cc * NC + t];
        out[g * NC + t] = a2 + bfc[t];
    }
}

// ---------------- launch ----------------

extern "C" void kernel_launch(void* const* d_in, const int* in_sizes, int n_in,
                              void* d_out, int out_size, void* d_ws, size_t ws_size,
                              hipStream_t stream) {
    const float* x    = (const float*)d_in[0];
    const int*   ei   = (const int*)d_in[1];
    const int*   batch= (const int*)d_in[2];
    const float* W1   = (const float*)d_in[3];
    const float* b1   = (const float*)d_in[4];
    const float* W2   = (const float*)d_in[5];
    const float* b2   = (const float*)d_in[6];
    const float* Wfc  = (const float*)d_in[7];
    const float* bfc  = (const float*)d_in[8];
    float* out = (float*)d_out;

    const int* src = ei;
    const int* dst = ei + NEDGES;

    // workspace (~66 MB):
    bhalf* xb        = (bhalf*)d_ws;                       // [N,128] bf16 (12.8 MB)
    bhalf* zb        = xb + (size_t)NNODES * FIN;          // [N,128] bf16 (12.8 MB)
    unsigned int* edata  = (unsigned int*)(zb + (size_t)NNODES * FIN);  // [E] {f16 dinv_d | src} (3.2 MB)
    unsigned int* binned = edata + NEDGES;                 // [NBUCK*BCAP] u32 (4.0 MB)
    int*   row_start = (int*)(binned + (size_t)NBUCK * BCAP);  // [N+256]
    int*   bcur      = row_start + NNODES + 256;           // [256] (memset to 0)
    float* dinv      = (float*)(bcur + 256);               // [N+256]
    bhalf* w1t       = (bhalf*)(dinv + NNODES + 256);      // [256,128] bf16
    unsigned short* wt16 = (unsigned short*)(w1t + 256 * FIN);  // [64,NP] f16 (6.4 MB)
    float* qg        = (float*)(wt16 + (size_t)NG * NP);   // [64,256] f32 (64 KB)
    float* qpart     = qg + (size_t)NG * FH;               // [782,64,128] f32 (25.7 MB)

    (void)hipMemsetAsync(bcur, 0, NBUCK * 4, stream);

    // ---- CSR build + norms + staging (bin range overlaps splitx range) ----
    k1_kernel<<<K1_BLOCKS, 512, 0, stream>>>(src, dst, bcur, binned, x, xb, W1, w1t);
    place_kernel<<<NBUCK, 512, 0, stream>>>(binned, bcur, row_start, dinv, edata);

    // conv1 aggregate: z = bf16(Ahat*x)
    gather128_kernel<<<(NNODES + 3) / 4, 256, 0, stream>>>(xb, edata, row_start, dinv,
                                                           zb, NNODES);
    // pooling-weight matrix straight to f16 from CSR
    wt_build_kernel<<<NG * 4, 512, 0, stream>>>(edata, row_start, batch, dinv, wt16);

    // fused: h1 = gelu(z@W1+b1) (LDS-only) ; qpart[blk] = wt_blk @ h1_blk
    gemmq_kernel<<<GEMM_BLKS, 256, 0, stream>>>(zb, w1t, b1, wt16, qpart, NNODES);

    // reduce qpart at full BW, then tiny head
    qreduce_kernel<<<NG * 4, 256, 0, stream>>>(qpart, qg);
    p2fc_kernel<<<NG, FH, 0, stream>>>(qg, W2, b2, batch, Wfc, bfc, out);
}

// Round 10
// 239.981 us; speedup vs baseline: 1.0216x; 1.0216x over previous
//
#include <hip/hip_runtime.h>
#include <hip/hip_bf16.h>
#include <hip/hip_fp16.h>
#include <math.h>

#define NNODES 50000
#define NEDGES 800000
#define FIN 128
#define FH 256
#define NG 64
#define NC 64
#define NP 50176              // node dim padded to 196*256
#define SPLITX_ITEMS (NNODES * FIN / 4)      // 1.6M
#define SPLITX_BLOCKS ((SPLITX_ITEMS + 511) / 512)   // 3125
#define W1T_BLOCKS (FIN * 256 / 512)         // 64
#define GEMM_MB ((NNODES + 127) / 128)       // 391
#define GEMM_BLKS (GEMM_MB * 2)              // 782
#define QTR (NP / 4)                         // 12544 src slots per wt-build block

#define NBUCK 196             // dst>>8 buckets (256 nodes each)
#define BCAP 5120             // per-bucket capacity (mean 4096, sigma ~64 -> +16 sigma)
#define BIN_CHUNK 2048        // edges per bin block
#define BIN_BLOCKS ((NEDGES + BIN_CHUNK - 1) / BIN_CHUNK)   // 391
#define K1_BLOCKS (BIN_BLOCKS + SPLITX_BLOCKS + W1T_BLOCKS) // 3580

typedef unsigned short bhalf;
typedef __attribute__((ext_vector_type(8))) short bf16x8;
typedef __attribute__((ext_vector_type(8))) _Float16 f16x8;
typedef __attribute__((ext_vector_type(4))) float f32x4;
typedef __attribute__((ext_vector_type(4))) unsigned short u16x4;

__device__ inline bhalf f2bf_rn(float f) {
    unsigned int u = __float_as_uint(f);
    u += 0x7FFFu + ((u >> 16) & 1u);      // round-to-nearest-even
    return (bhalf)(u >> 16);
}
__device__ inline float2 bfpair(unsigned int u) {   // [lo16, hi16] -> two floats
    return make_float2(__uint_as_float(u << 16), __uint_as_float(u & 0xFFFF0000u));
}

// ---------------- K1 (512 thr): bin (blocks 0..390) | x->bf16 | W1 transpose ----------------

__global__ __launch_bounds__(512)
void k1_kernel(const int* __restrict__ src, const int* __restrict__ dst,
               int* __restrict__ bcur, unsigned int* __restrict__ binned,
               const float* __restrict__ x, bhalf* __restrict__ xb,
               const float* __restrict__ W1, bhalf* __restrict__ w1t) {
    int t = threadIdx.x;
    if (blockIdx.x >= BIN_BLOCKS) {
        int b = blockIdx.x - BIN_BLOCKS;
        if (b < SPLITX_BLOCKS) {
            int i = b * 512 + t;
            if (i < SPLITX_ITEMS) {
                float4 v = *reinterpret_cast<const float4*>(&x[i * 4]);
                u16x4 o = {f2bf_rn(v.x), f2bf_rn(v.y), f2bf_rn(v.z), f2bf_rn(v.w)};
                *reinterpret_cast<u16x4*>(&xb[i * 4]) = o;
            }
        } else {
            int i = (b - SPLITX_BLOCKS) * 512 + t;     // W1[K][256] -> w1t[256][K]
            int k = i >> 8, n = i & 255;
            w1t[n * FIN + k] = f2bf_rn(W1[i]);
        }
        return;
    }
    // ---- bin range: 4B entries {dlo:8 | src:16}, staged bucket-major in LDS ----
    __shared__ int hist[NBUCK];
    __shared__ int base[NBUCK];
    __shared__ int gb[NBUCK];
    __shared__ int lcur[NBUCK];
    __shared__ int scan_tmp[256];
    __shared__ unsigned int stage[BIN_CHUNK];
    __shared__ unsigned char bid[BIN_CHUNK];
    int e0 = blockIdx.x * BIN_CHUNK;
    for (int i = t; i < NBUCK; i += 512) hist[i] = 0;
    __syncthreads();
#pragma unroll
    for (int k = 0; k < BIN_CHUNK / 512; k++) {
        int e = e0 + k * 512 + t;
        if (e < NEDGES) atomicAdd(&hist[dst[e] >> 8], 1);
    }
    __syncthreads();
    int v = (t < NBUCK) ? hist[t] : 0;
    if (t < 256) scan_tmp[t] = v;
    __syncthreads();
#pragma unroll
    for (int off = 1; off < 256; off <<= 1) {
        int xx = (t >= off && t < 256) ? scan_tmp[t - off] : 0;
        __syncthreads();
        if (t < 256) scan_tmp[t] += xx;
        __syncthreads();
    }
    if (t < NBUCK) {
        int ex = scan_tmp[t] - v;                // exclusive
        base[t] = ex;
        lcur[t] = ex;
        gb[t] = (v > 0) ? atomicAdd(&bcur[t], v) : 0;   // bcur counts from 0
    }
    __syncthreads();
#pragma unroll
    for (int k = 0; k < BIN_CHUNK / 512; k++) {
        int e = e0 + k * 512 + t;
        if (e < NEDGES) {
            int s = src[e], d = dst[e];
            int b = d >> 8;
            int lp = atomicAdd(&lcur[b], 1);
            stage[lp] = (unsigned int)s | ((unsigned int)(d & 255) << 16);
            bid[lp] = (unsigned char)b;          // b < 196 fits u8
        }
    }
    __syncthreads();
    int total = base[NBUCK - 1] + hist[NBUCK - 1];
    for (int i = t; i < total; i += 512) {
        int b = bid[i];
        binned[(size_t)b * BCAP + gb[b] + (i - base[b])] = stage[i];
    }
}

// ---------------- pass 2 (512 thr): per-bucket degree+dinv+row_start+CSR placement ----------------

__global__ __launch_bounds__(512)
void place_kernel(const unsigned int* __restrict__ binned, const int* __restrict__ bcur,
                  int* __restrict__ row_start, float* __restrict__ dinv,
                  unsigned int* __restrict__ edata) {
    __shared__ unsigned int stage[BCAP];
    __shared__ int sc[256];
    __shared__ int deg[256];
    __shared__ int lex[256];
    __shared__ int lcur[256];
    __shared__ unsigned short dih[256];
    __shared__ int s_ebase, s_cnt;
    int b = blockIdx.x, t = threadIdx.x;
    // exclusive prefix over bucket counts -> global edge base of this bucket
    int c = (t < NBUCK) ? bcur[t] : 0;
    if (t < 256) sc[t] = c;
    __syncthreads();
#pragma unroll
    for (int off = 1; off < 256; off <<= 1) {
        int x = (t >= off && t < 256) ? sc[t - off] : 0;
        __syncthreads();
        if (t < 256) sc[t] += x;
        __syncthreads();
    }
    if (t == b) { s_ebase = sc[t] - c; s_cnt = c; }
    if (t < 256) deg[t] = 0;
    __syncthreads();
    int cnt = s_cnt, eb = s_ebase;
    const unsigned int* bp = &binned[(size_t)b * BCAP];
    for (int i = t; i < cnt; i += 512) stage[i] = bp[i];
    __syncthreads();
    for (int i = t; i < cnt; i += 512) atomicAdd(&deg[(stage[i] >> 16) & 255], 1);
    __syncthreads();
    int d = (t < 256) ? deg[t] : 0;
    if (t < 256) {
        float di = rsqrtf((float)d + 1.0f);
        int gn = (b << 8) + t;
        if (gn < NNODES) dinv[gn] = di;
        dih[t] = __half_as_ushort(__float2half(di));
        sc[t] = d;
    }
    __syncthreads();
#pragma unroll
    for (int off = 1; off < 256; off <<= 1) {
        int x = (t >= off && t < 256) ? sc[t - off] : 0;
        __syncthreads();
        if (t < 256) sc[t] += x;
        __syncthreads();
    }
    if (t < 256) {
        int lexv = sc[t] - d;                    // exclusive within bucket
        lex[t] = lexv;
        lcur[t] = 0;
        int gn = (b << 8) + t;
        if (gn <= NNODES) row_start[gn] = eb + lexv;  // row_start[N] = E lands here too
    }
    __syncthreads();
    for (int i = t; i < cnt; i += 512) {
        unsigned int e = stage[i];
        int dl = (e >> 16) & 255;
        int pos = eb + lex[dl] + atomicAdd(&lcur[dl], 1);
        edata[pos] = (e & 0xFFFFu) | ((unsigned int)dih[dl] << 16);
    }
}

// ---------------- CSR gather, 128 bf16 feats, factored norms, unroll-8 MLP ----------------

__global__ __launch_bounds__(256)
void gather128_kernel(const bhalf* __restrict__ xb, const unsigned int* __restrict__ edata,
                      const int* __restrict__ row_start, const float* __restrict__ dinv,
                      bhalf* __restrict__ z, int Nn) {
    int node = blockIdx.x * 4 + (threadIdx.x >> 6);
    if (node >= Nn) return;
    int lane = threadIdx.x & 63;
    int st = row_start[node];
    int cnt = row_start[node + 1] - st;
    float ax = 0.0f, ay = 0.0f;
    int j = 0;
    for (; j + 7 < cnt; j += 8) {
        unsigned int e[8];
        float2 v[8];
#pragma unroll
        for (int u = 0; u < 8; u++) e[u] = edata[st + j + u];
#pragma unroll
        for (int u = 0; u < 8; u++)
            v[u] = bfpair(*reinterpret_cast<const unsigned int*>(
                &xb[(size_t)(e[u] & 0xFFFFu) * FIN + lane * 2]));
#pragma unroll
        for (int u = 0; u < 8; u++) {
            float n = dinv[e[u] & 0xFFFFu];
            ax += v[u].x * n;
            ay += v[u].y * n;
        }
    }
    for (; j < cnt; j++) {
        unsigned int e0 = edata[st + j];
        int s0 = e0 & 0xFFFFu;
        float2 v0 = bfpair(*reinterpret_cast<const unsigned int*>(&xb[(size_t)s0 * FIN + lane * 2]));
        float n0 = dinv[s0];
        ax += v0.x * n0; ay += v0.y * n0;
    }
    float dn = dinv[node];
    float2 xv = bfpair(*reinterpret_cast<const unsigned int*>(&xb[(size_t)node * FIN + lane * 2]));
    ushort2 o = {f2bf_rn(dn * (ax + xv.x * dn)), f2bf_rn(dn * (ay + xv.y * dn))};
    *reinterpret_cast<ushort2*>(&z[(size_t)node * FIN + lane * 2]) = o;
}

// ---------------- wt build (512 thr): single f16 array ----------------

__global__ __launch_bounds__(512)
void wt_build_kernel(const unsigned int* __restrict__ edata, const int* __restrict__ row_start,
                     const int* __restrict__ batch, const float* __restrict__ dinv,
                     unsigned short* __restrict__ wt16) {
    __shared__ float acc[QTR];
    int g = blockIdx.x >> 2;
    int q = blockIdx.x & 3;
    int base = q * QTR;
    for (int i = threadIdx.x; i < QTR; i += 512) acc[i] = 0.0f;
    // node range [na, nb) of graph g (batch sorted)
    int lo = 0, hi = NNODES;
    while (lo < hi) { int m = (lo + hi) >> 1; if (batch[m] < g) lo = m + 1; else hi = m; }
    int na = lo;
    hi = NNODES;               // nb >= na since sorted
    while (lo < hi) { int m = (lo + hi) >> 1; if (batch[m] < g + 1) lo = m + 1; else hi = m; }
    int nb = lo;
    int pa = row_start[na];
    int pb = row_start[nb];
    __syncthreads();
    for (int p = pa + threadIdx.x; p < pb; p += 512) {
        unsigned int e = edata[p];
        int s = (int)(e & 0xFFFFu) - base;
        if ((unsigned int)s < (unsigned int)QTR)
            atomicAdd(&acc[s], __half2float(__ushort_as_half((unsigned short)(e >> 16))));
    }
    __syncthreads();
    size_t rowo = (size_t)g * NP + base;
    for (int i = threadIdx.x; i < QTR; i += 512) {
        int s = base + i;
        float dv = (s < NNODES) ? dinv[s] : 0.0f;
        float v = acc[i];
        if (s >= na && s < nb) v += dv;          // self-loop (becomes dinv^2)
        v *= dv;
        wt16[rowo + i] = __half_as_ushort(__float2half(v));
    }
}

// ---------------- fused GEMM + q-partial (LDS-staged phase A; best-measured r8 form) ----------------

__global__ __launch_bounds__(256)
void gemmq_kernel(const bhalf* __restrict__ A, const bhalf* __restrict__ Bt,
                  const float* __restrict__ bias, const unsigned short* __restrict__ wt16,
                  float* __restrict__ qpart, int M) {
    __shared__ alignas(16) bhalf smem[2 * 128 * 72];   // As|Bs, reused as h1s[128][136]
    bhalf* As = smem;
    bhalf* Bs = smem + 128 * 72;
    const int tid  = threadIdx.x;
    const int lane = tid & 63;
    const int wave = tid >> 6;
    const int quad = lane >> 4;
    const int l15  = lane & 15;
    const int wm = (wave & 1) * 64;
    const int wn = (wave >> 1) * 64;
    const int bm = (blockIdx.x >> 1) * 128;
    const int bn = (blockIdx.x & 1) * 128;

    // ---- prefetch ALL phase-C wt fragments (16 x 16B = 64 VGPR) ----
    f16x8 wreg[4][4];
#pragma unroll
    for (int ki = 0; ki < 4; ki++)
#pragma unroll
        for (int gt = 0; gt < 4; gt++)
            wreg[ki][gt] = *reinterpret_cast<const f16x8*>(
                &wt16[(size_t)(gt * 16 + l15) * NP + bm + ki * 32 + quad * 8]);

    f32x4 acc[4][4] = {};

    for (int k0 = 0; k0 < FIN; k0 += 64) {
#pragma unroll
        for (int i = 0; i < 4; i++) {
            int chunk = tid + i * 256;           // 1024 chunks of 8 bf16
            int r = chunk >> 3, c16 = chunk & 7;
            int gm = bm + r;
            float4 va = make_float4(0.f, 0.f, 0.f, 0.f);
            if (gm < M) va = *reinterpret_cast<const float4*>(&A[(size_t)gm * FIN + k0 + c16 * 8]);
            *reinterpret_cast<float4*>(&As[r * 72 + c16 * 8]) = va;
            float4 vb = *reinterpret_cast<const float4*>(&Bt[(size_t)(bn + r) * FIN + k0 + c16 * 8]);
            *reinterpret_cast<float4*>(&Bs[r * 72 + c16 * 8]) = vb;
        }
        __syncthreads();
#pragma unroll
        for (int kk = 0; kk < 64; kk += 32) {
            bf16x8 af[4], bfr[4];
#pragma unroll
            for (int mi = 0; mi < 4; mi++)
                af[mi] = *reinterpret_cast<const bf16x8*>(&As[(wm + mi * 16 + l15) * 72 + kk + quad * 8]);
#pragma unroll
            for (int ni = 0; ni < 4; ni++)
                bfr[ni] = *reinterpret_cast<const bf16x8*>(&Bs[(wn + ni * 16 + l15) * 72 + kk + quad * 8]);
#pragma unroll
            for (int mi = 0; mi < 4; mi++)
#pragma unroll
                for (int ni = 0; ni < 4; ni++)
                    acc[mi][ni] = __builtin_amdgcn_mfma_f32_16x16x32_bf16(af[mi], bfr[ni], acc[mi][ni], 0, 0, 0);
        }
        __syncthreads();
    }

    // Phase B: gelu -> f16 -> LDS h1s[col][node] (overlays As/Bs; safe after barrier)
    bhalf* h1s = smem;                           // [128][136] (f16 bits)
#pragma unroll
    for (int mi = 0; mi < 4; mi++) {
        int node0 = wm + mi * 16 + quad * 4;     // local node (row)
#pragma unroll
        for (int ni = 0; ni < 4; ni++) {
            int col = wn + ni * 16 + l15;        // local h-col
            float bv = bias[bn + col];
            u16x4 o;
#pragma unroll
            for (int r = 0; r < 4; r++) {
                float v = acc[mi][ni][r] + bv;
                v = 0.5f * v * (1.0f + erff(v * 0.70710678118654752f));
                o[r] = __half_as_ushort(__float2half(v));
            }
            *reinterpret_cast<u16x4*>(&h1s[col * 136 + node0]) = o;
        }
    }
    __syncthreads();

    // Phase C: q-partial. A = wt16 (rows=g, contraction=node, in regs), B = h1s.
    f32x4 qacc[4][2] = {};
    const int c0 = wave * 32;                    // this wave's 32-col slice
#pragma unroll
    for (int ki = 0; ki < 4; ki++) {
        f16x8 bfr2[2];
#pragma unroll
        for (int ct = 0; ct < 2; ct++)
            bfr2[ct] = *reinterpret_cast<const f16x8*>(&h1s[(c0 + ct * 16 + l15) * 136 + ki * 32 + quad * 8]);
#pragma unroll
        for (int gt = 0; gt < 4; gt++)
#pragma unroll
            for (int ct = 0; ct < 2; ct++)
                qacc[gt][ct] = __builtin_amdgcn_mfma_f32_16x16x32_f16(wreg[ki][gt], bfr2[ct], qacc[gt][ct], 0, 0, 0);
    }
    // store: qpart[blk][g][col]; C layout: row(g)=gt*16+quad*4+r, col=c0+ct*16+l15
    float* qp = &qpart[(size_t)blockIdx.x * NG * 128];
#pragma unroll
    for (int gt = 0; gt < 4; gt++) {
#pragma unroll
        for (int ct = 0; ct < 2; ct++) {
            int col = c0 + ct * 16 + l15;
#pragma unroll
            for (int r = 0; r < 4; r++)
                qp[(gt * 16 + quad * 4 + r) * 128 + col] = qacc[gt][ct][r];
        }
    }
}

// ---------------- qpart reduce at full chip BW: qg[g][k] = sum_blk qpart ----------------

__global__ __launch_bounds__(256)
void qreduce_kernel(const float* __restrict__ qpart, float* __restrict__ qg) {
    __shared__ float red[256];
    int g = blockIdx.x >> 2;
    int chunk = blockIdx.x & 3;
    int half = chunk >> 1;
    int col128 = (chunk & 1) * 64 + (threadIdx.x & 63);
    int mi = threadIdx.x >> 6;
    float s = 0.0f;
    for (int m = mi; m < GEMM_MB; m += 4)
        s += qpart[(size_t)(m * 2 + half) * NG * 128 + (size_t)g * 128 + col128];
    red[threadIdx.x] = s;
    __syncthreads();
    if (mi == 0) {
        int kc = threadIdx.x;
        qg[(size_t)g * FH + half * 128 + col128] =
            red[kc] + red[64 + kc] + red[128 + kc] + red[192 + kc];
    }
}

// ---------------- fused head: pooled = (qg@W2)/cnt + b2 ; out = pooled@Wfc + bfc ----------------

__global__ __launch_bounds__(256)
void p2fc_kernel(const float* __restrict__ qg, const float* __restrict__ W2,
                 const float* __restrict__ b2, const int* __restrict__ batch,
                 const float* __restrict__ Wfc, const float* __restrict__ bfc,
                 float* __restrict__ out) {
    __shared__ float qgl[FH];
    __shared__ float ps[FH];
    int g = blockIdx.x;
    int t = threadIdx.x;
    qgl[t] = qg[(size_t)g * FH + t];
    int lo = 0, hi = NNODES;
    while (lo < hi) { int m = (lo + hi) >> 1; if (batch[m] < g) lo = m + 1; else hi = m; }
    int a = lo;
    lo = 0; hi = NNODES;
    while (lo < hi) { int m = (lo + hi) >> 1; if (batch[m] < g + 1) lo = m + 1; else hi = m; }
    float inv = 1.0f / fmaxf((float)(lo - a), 1.0f);
    __syncthreads();
    float acc = 0.0f;
    for (int k = 0; k < FH; k++)
        acc += qgl[k] * W2[k * FH + t];
    ps[t] = acc * inv + b2[t];
    __syncthreads();
    if (t < NC) {
        float a2 = 0.0f;
        for (int cc = 0; cc < FH; cc++)
            a2 += ps[cc] * Wfc[cc * NC + t];
        out[g * NC + t] = a2 + bfc[t];
    }
}

// ---------------- launch ----------------

extern "C" void kernel_launch(void* const* d_in, const int* in_sizes, int n_in,
                              void* d_out, int out_size, void* d_ws, size_t ws_size,
                              hipStream_t stream) {
    const float* x    = (const float*)d_in[0];
    const int*   ei   = (const int*)d_in[1];
    const int*   batch= (const int*)d_in[2];
    const float* W1   = (const float*)d_in[3];
    const float* b1   = (const float*)d_in[4];
    const float* W2   = (const float*)d_in[5];
    const float* b2   = (const float*)d_in[6];
    const float* Wfc  = (const float*)d_in[7];
    const float* bfc  = (const float*)d_in[8];
    float* out = (float*)d_out;

    const int* src = ei;
    const int* dst = ei + NEDGES;

    // workspace (~66 MB):
    bhalf* xb        = (bhalf*)d_ws;                       // [N,128] bf16 (12.8 MB)
    bhalf* zb        = xb + (size_t)NNODES * FIN;          // [N,128] bf16 (12.8 MB)
    unsigned int* edata  = (unsigned int*)(zb + (size_t)NNODES * FIN);  // [E] {f16 dinv_d | src} (3.2 MB)
    unsigned int* binned = edata + NEDGES;                 // [NBUCK*BCAP] u32 (4.0 MB)
    int*   row_start = (int*)(binned + (size_t)NBUCK * BCAP);  // [N+256]
    int*   bcur      = row_start + NNODES + 256;           // [256] (memset to 0)
    float* dinv      = (float*)(bcur + 256);               // [N+256]
    bhalf* w1t       = (bhalf*)(dinv + NNODES + 256);      // [256,128] bf16
    unsigned short* wt16 = (unsigned short*)(w1t + 256 * FIN);  // [64,NP] f16 (6.4 MB)
    float* qg        = (float*)(wt16 + (size_t)NG * NP);   // [64,256] f32 (64 KB)
    float* qpart     = qg + (size_t)NG * FH;               // [782,64,128] f32 (25.7 MB)

    (void)hipMemsetAsync(bcur, 0, NBUCK * 4, stream);

    // ---- CSR build + norms + staging (bin range overlaps splitx range) ----
    k1_kernel<<<K1_BLOCKS, 512, 0, stream>>>(src, dst, bcur, binned, x, xb, W1, w1t);
    place_kernel<<<NBUCK, 512, 0, stream>>>(binned, bcur, row_start, dinv, edata);

    // conv1 aggregate: z = bf16(Ahat*x)
    gather128_kernel<<<(NNODES + 3) / 4, 256, 0, stream>>>(xb, edata, row_start, dinv,
                                                           zb, NNODES);
    // pooling-weight matrix straight to f16 from CSR
    wt_build_kernel<<<NG * 4, 512, 0, stream>>>(edata, row_start, batch, dinv, wt16);

    // fused: h1 = gelu(z@W1+b1) (LDS-only) ; qpart[blk] = wt_blk @ h1_blk
    gemmq_kernel<<<GEMM_BLKS, 256, 0, stream>>>(zb, w1t, b1, wt16, qpart, NNODES);

    // reduce qpart at full BW, then tiny head
    qreduce_kernel<<<NG * 4, 256, 0, stream>>>(qpart, qg);
    p2fc_kernel<<<NG, FH, 0, stream>>>(qg, W2, b2, batch, Wfc, bfc, out);
}

// Round 11
// 238.956 us; speedup vs baseline: 1.0260x; 1.0043x over previous
//
#include <hip/hip_runtime.h>
#include <hip/hip_bf16.h>
#include <hip/hip_fp16.h>
#include <math.h>

#define NNODES 50000
#define NEDGES 800000
#define FIN 128
#define FH 256
#define NG 64
#define NC 64
#define NP 50176              // node dim padded to 196*256
#define SPLITX_ITEMS (NNODES * FIN / 4)      // 1.6M
#define SPLITX_BLOCKS ((SPLITX_ITEMS + 511) / 512)   // 3125
#define W1T_BLOCKS (FIN * 256 / 512)         // 64
#define GEMM_MB ((NNODES + 127) / 128)       // 391
#define GEMM_BLKS (GEMM_MB * 2)              // 782
#define QTR (NP / 4)                         // 12544 src slots per wt-build block

#define NBUCK 196             // dst>>8 buckets (256 nodes each)
#define BCAP 5120             // per-bucket capacity (mean 4096, sigma ~64 -> +16 sigma)
#define BIN_CHUNK 2048        // edges per bin block
#define BIN_BLOCKS ((NEDGES + BIN_CHUNK - 1) / BIN_CHUNK)   // 391
#define K1_BLOCKS (BIN_BLOCKS + SPLITX_BLOCKS + W1T_BLOCKS) // 3580

typedef unsigned short bhalf;
typedef __attribute__((ext_vector_type(8))) short bf16x8;
typedef __attribute__((ext_vector_type(8))) _Float16 f16x8;
typedef __attribute__((ext_vector_type(4))) float f32x4;
typedef __attribute__((ext_vector_type(4))) unsigned short u16x4;

__device__ inline bhalf f2bf_rn(float f) {
    unsigned int u = __float_as_uint(f);
    u += 0x7FFFu + ((u >> 16) & 1u);      // round-to-nearest-even
    return (bhalf)(u >> 16);
}
__device__ inline float2 bfpair(unsigned int u) {   // [lo16, hi16] -> two floats
    return make_float2(__uint_as_float(u << 16), __uint_as_float(u & 0xFFFF0000u));
}

// ---------------- K1 (512 thr): bin (blocks 0..390) | x->bf16 | W1 transpose ----------------

__global__ __launch_bounds__(512)
void k1_kernel(const int* __restrict__ src, const int* __restrict__ dst,
               int* __restrict__ bcur, unsigned int* __restrict__ binned,
               const float* __restrict__ x, bhalf* __restrict__ xb,
               const float* __restrict__ W1, bhalf* __restrict__ w1t) {
    int t = threadIdx.x;
    if (blockIdx.x >= BIN_BLOCKS) {
        int b = blockIdx.x - BIN_BLOCKS;
        if (b < SPLITX_BLOCKS) {
            int i = b * 512 + t;
            if (i < SPLITX_ITEMS) {
                float4 v = *reinterpret_cast<const float4*>(&x[i * 4]);
                u16x4 o = {f2bf_rn(v.x), f2bf_rn(v.y), f2bf_rn(v.z), f2bf_rn(v.w)};
                *reinterpret_cast<u16x4*>(&xb[i * 4]) = o;
            }
        } else {
            int i = (b - SPLITX_BLOCKS) * 512 + t;     // W1[K][256] -> w1t[256][K]
            int k = i >> 8, n = i & 255;
            w1t[n * FIN + k] = f2bf_rn(W1[i]);
        }
        return;
    }
    // ---- bin range: 4B entries {dlo:8 | src:16}, staged bucket-major in LDS ----
    __shared__ int hist[NBUCK];
    __shared__ int base[NBUCK];
    __shared__ int gb[NBUCK];
    __shared__ int lcur[NBUCK];
    __shared__ int scan_tmp[256];
    __shared__ unsigned int stage[BIN_CHUNK];
    __shared__ unsigned char bid[BIN_CHUNK];
    int e0 = blockIdx.x * BIN_CHUNK;
    for (int i = t; i < NBUCK; i += 512) hist[i] = 0;
    __syncthreads();
#pragma unroll
    for (int k = 0; k < BIN_CHUNK / 512; k++) {
        int e = e0 + k * 512 + t;
        if (e < NEDGES) atomicAdd(&hist[dst[e] >> 8], 1);
    }
    __syncthreads();
    int v = (t < NBUCK) ? hist[t] : 0;
    if (t < 256) scan_tmp[t] = v;
    __syncthreads();
#pragma unroll
    for (int off = 1; off < 256; off <<= 1) {
        int xx = (t >= off && t < 256) ? scan_tmp[t - off] : 0;
        __syncthreads();
        if (t < 256) scan_tmp[t] += xx;
        __syncthreads();
    }
    if (t < NBUCK) {
        int ex = scan_tmp[t] - v;                // exclusive
        base[t] = ex;
        lcur[t] = ex;
        gb[t] = (v > 0) ? atomicAdd(&bcur[t], v) : 0;   // bcur counts from 0
    }
    __syncthreads();
#pragma unroll
    for (int k = 0; k < BIN_CHUNK / 512; k++) {
        int e = e0 + k * 512 + t;
        if (e < NEDGES) {
            int s = src[e], d = dst[e];
            int b = d >> 8;
            int lp = atomicAdd(&lcur[b], 1);
            stage[lp] = (unsigned int)s | ((unsigned int)(d & 255) << 16);
            bid[lp] = (unsigned char)b;          // b < 196 fits u8
        }
    }
    __syncthreads();
    int total = base[NBUCK - 1] + hist[NBUCK - 1];
    for (int i = t; i < total; i += 512) {
        int b = bid[i];
        binned[(size_t)b * BCAP + gb[b] + (i - base[b])] = stage[i];
    }
}

// ---------------- pass 2 (512 thr): per-bucket degree+dinv+row_start+CSR placement ----------------

__global__ __launch_bounds__(512)
void place_kernel(const unsigned int* __restrict__ binned, const int* __restrict__ bcur,
                  int* __restrict__ row_start, float* __restrict__ dinv,
                  unsigned int* __restrict__ edata) {
    __shared__ unsigned int stage[BCAP];
    __shared__ int sc[256];
    __shared__ int deg[256];
    __shared__ int lex[256];
    __shared__ int lcur[256];
    __shared__ unsigned short dih[256];
    __shared__ int s_ebase, s_cnt;
    int b = blockIdx.x, t = threadIdx.x;
    // exclusive prefix over bucket counts -> global edge base of this bucket
    int c = (t < NBUCK) ? bcur[t] : 0;
    if (t < 256) sc[t] = c;
    __syncthreads();
#pragma unroll
    for (int off = 1; off < 256; off <<= 1) {
        int x = (t >= off && t < 256) ? sc[t - off] : 0;
        __syncthreads();
        if (t < 256) sc[t] += x;
        __syncthreads();
    }
    if (t == b) { s_ebase = sc[t] - c; s_cnt = c; }
    if (t < 256) deg[t] = 0;
    __syncthreads();
    int cnt = s_cnt, eb = s_ebase;
    const unsigned int* bp = &binned[(size_t)b * BCAP];
    for (int i = t; i < cnt; i += 512) stage[i] = bp[i];
    __syncthreads();
    for (int i = t; i < cnt; i += 512) atomicAdd(&deg[(stage[i] >> 16) & 255], 1);
    __syncthreads();
    int d = (t < 256) ? deg[t] : 0;
    if (t < 256) {
        float di = rsqrtf((float)d + 1.0f);
        int gn = (b << 8) + t;
        if (gn < NNODES) dinv[gn] = di;
        dih[t] = __half_as_ushort(__float2half(di));
        sc[t] = d;
    }
    __syncthreads();
#pragma unroll
    for (int off = 1; off < 256; off <<= 1) {
        int x = (t >= off && t < 256) ? sc[t - off] : 0;
        __syncthreads();
        if (t < 256) sc[t] += x;
        __syncthreads();
    }
    if (t < 256) {
        int lexv = sc[t] - d;                    // exclusive within bucket
        lex[t] = lexv;
        lcur[t] = 0;
        int gn = (b << 8) + t;
        if (gn <= NNODES) row_start[gn] = eb + lexv;  // row_start[N] = E lands here too
    }
    __syncthreads();
    for (int i = t; i < cnt; i += 512) {
        unsigned int e = stage[i];
        int dl = (e >> 16) & 255;
        int pos = eb + lex[dl] + atomicAdd(&lcur[dl], 1);
        edata[pos] = (e & 0xFFFFu) | ((unsigned int)dih[dl] << 16);
    }
}

// ---------------- CSR gather, half-wave edge-pairing: 16 edges in flight ----------------
// Lanes 0-31 handle even edges, 32-63 odd edges; each lane loads 8B (4 bf16)
// of the source row -> one wave-wide load fetches TWO rows (same 4-line
// traffic). Halves fold via __shfl_xor(.,32) at the end. Doubles MLP and
// halves instruction count per edge vs the 4B/lane unroll-8 version.

__global__ __launch_bounds__(256)
void gather128_kernel(const bhalf* __restrict__ xb, const unsigned int* __restrict__ edata,
                      const int* __restrict__ row_start, const float* __restrict__ dinv,
                      bhalf* __restrict__ z, int Nn) {
    int node = blockIdx.x * 4 + (threadIdx.x >> 6);
    if (node >= Nn) return;
    int lane = threadIdx.x & 63;
    int half = lane >> 5;                        // 0: even edges, 1: odd edges
    int l31 = lane & 31;                         // feature block: 4 bf16 at l31*4
    int st = row_start[node];
    int cnt = row_start[node + 1] - st;
    float a0 = 0.0f, a1 = 0.0f, a2 = 0.0f, a3 = 0.0f;
    int j = 0;
    for (; j + 15 < cnt; j += 16) {              // 8 pair-slots = 16 edges in flight
        unsigned int e[8];
        uint2 v[8];
#pragma unroll
        for (int u = 0; u < 8; u++) e[u] = edata[st + j + 2 * u + half];
#pragma unroll
        for (int u = 0; u < 8; u++)
            v[u] = *reinterpret_cast<const uint2*>(
                &xb[(size_t)(e[u] & 0xFFFFu) * FIN + l31 * 4]);
#pragma unroll
        for (int u = 0; u < 8; u++) {
            float n = dinv[e[u] & 0xFFFFu];
            float2 p0 = bfpair(v[u].x), p1 = bfpair(v[u].y);
            a0 += p0.x * n; a1 += p0.y * n; a2 += p1.x * n; a3 += p1.y * n;
        }
    }
    for (; j + 1 < cnt; j += 2) {                // pair tail
        unsigned int e0 = edata[st + j + half];
        uint2 v0 = *reinterpret_cast<const uint2*>(
            &xb[(size_t)(e0 & 0xFFFFu) * FIN + l31 * 4]);
        float n0 = dinv[e0 & 0xFFFFu];
        float2 p0 = bfpair(v0.x), p1 = bfpair(v0.y);
        a0 += p0.x * n0; a1 += p0.y * n0; a2 += p1.x * n0; a3 += p1.y * n0;
    }
    if (j < cnt) {                               // single tail: half 1 contributes 0
        unsigned int e0 = edata[st + j];
        uint2 v0 = *reinterpret_cast<const uint2*>(
            &xb[(size_t)(e0 & 0xFFFFu) * FIN + l31 * 4]);
        float n0 = half ? 0.0f : dinv[e0 & 0xFFFFu];
        float2 p0 = bfpair(v0.x), p1 = bfpair(v0.y);
        a0 += p0.x * n0; a1 += p0.y * n0; a2 += p1.x * n0; a3 += p1.y * n0;
    }
    // fold odd-edge half into even-edge half (and vice versa; both get the sum)
    a0 += __shfl_xor(a0, 32);
    a1 += __shfl_xor(a1, 32);
    a2 += __shfl_xor(a2, 32);
    a3 += __shfl_xor(a3, 32);
    float dn = dinv[node];
    uint2 xv = *reinterpret_cast<const uint2*>(&xb[(size_t)node * FIN + l31 * 4]);
    float2 x0 = bfpair(xv.x), x1 = bfpair(xv.y);
    if (half == 0) {                             // 32 lanes x 8B = 256B row write
        u16x4 o = {f2bf_rn(dn * (a0 + x0.x * dn)), f2bf_rn(dn * (a1 + x0.y * dn)),
                   f2bf_rn(dn * (a2 + x1.x * dn)), f2bf_rn(dn * (a3 + x1.y * dn))};
        *reinterpret_cast<u16x4*>(&z[(size_t)node * FIN + l31 * 4]) = o;
    }
}

// ---------------- wt build (512 thr): single f16 array ----------------

__global__ __launch_bounds__(512)
void wt_build_kernel(const unsigned int* __restrict__ edata, const int* __restrict__ row_start,
                     const int* __restrict__ batch, const float* __restrict__ dinv,
                     unsigned short* __restrict__ wt16) {
    __shared__ float acc[QTR];
    int g = blockIdx.x >> 2;
    int q = blockIdx.x & 3;
    int base = q * QTR;
    for (int i = threadIdx.x; i < QTR; i += 512) acc[i] = 0.0f;
    // node range [na, nb) of graph g (batch sorted)
    int lo = 0, hi = NNODES;
    while (lo < hi) { int m = (lo + hi) >> 1; if (batch[m] < g) lo = m + 1; else hi = m; }
    int na = lo;
    hi = NNODES;               // nb >= na since sorted
    while (lo < hi) { int m = (lo + hi) >> 1; if (batch[m] < g + 1) lo = m + 1; else hi = m; }
    int nb = lo;
    int pa = row_start[na];
    int pb = row_start[nb];
    __syncthreads();
    for (int p = pa + threadIdx.x; p < pb; p += 512) {
        unsigned int e = edata[p];
        int s = (int)(e & 0xFFFFu) - base;
        if ((unsigned int)s < (unsigned int)QTR)
            atomicAdd(&acc[s], __half2float(__ushort_as_half((unsigned short)(e >> 16))));
    }
    __syncthreads();
    size_t rowo = (size_t)g * NP + base;
    for (int i = threadIdx.x; i < QTR; i += 512) {
        int s = base + i;
        float dv = (s < NNODES) ? dinv[s] : 0.0f;
        float v = acc[i];
        if (s >= na && s < nb) v += dv;          // self-loop (becomes dinv^2)
        v *= dv;
        wt16[rowo + i] = __half_as_ushort(__float2half(v));
    }
}

// ---------------- fused GEMM + q-partial (LDS-staged phase A; best-measured r8 form) ----------------

__global__ __launch_bounds__(256)
void gemmq_kernel(const bhalf* __restrict__ A, const bhalf* __restrict__ Bt,
                  const float* __restrict__ bias, const unsigned short* __restrict__ wt16,
                  float* __restrict__ qpart, int M) {
    __shared__ alignas(16) bhalf smem[2 * 128 * 72];   // As|Bs, reused as h1s[128][136]
    bhalf* As = smem;
    bhalf* Bs = smem + 128 * 72;
    const int tid  = threadIdx.x;
    const int lane = tid & 63;
    const int wave = tid >> 6;
    const int quad = lane >> 4;
    const int l15  = lane & 15;
    const int wm = (wave & 1) * 64;
    const int wn = (wave >> 1) * 64;
    const int bm = (blockIdx.x >> 1) * 128;
    const int bn = (blockIdx.x & 1) * 128;

    // ---- prefetch ALL phase-C wt fragments (16 x 16B = 64 VGPR) ----
    f16x8 wreg[4][4];
#pragma unroll
    for (int ki = 0; ki < 4; ki++)
#pragma unroll
        for (int gt = 0; gt < 4; gt++)
            wreg[ki][gt] = *reinterpret_cast<const f16x8*>(
                &wt16[(size_t)(gt * 16 + l15) * NP + bm + ki * 32 + quad * 8]);

    f32x4 acc[4][4] = {};

    for (int k0 = 0; k0 < FIN; k0 += 64) {
#pragma unroll
        for (int i = 0; i < 4; i++) {
            int chunk = tid + i * 256;           // 1024 chunks of 8 bf16
            int r = chunk >> 3, c16 = chunk & 7;
            int gm = bm + r;
            float4 va = make_float4(0.f, 0.f, 0.f, 0.f);
            if (gm < M) va = *reinterpret_cast<const float4*>(&A[(size_t)gm * FIN + k0 + c16 * 8]);
            *reinterpret_cast<float4*>(&As[r * 72 + c16 * 8]) = va;
            float4 vb = *reinterpret_cast<const float4*>(&Bt[(size_t)(bn + r) * FIN + k0 + c16 * 8]);
            *reinterpret_cast<float4*>(&Bs[r * 72 + c16 * 8]) = vb;
        }
        __syncthreads();
#pragma unroll
        for (int kk = 0; kk < 64; kk += 32) {
            bf16x8 af[4], bfr[4];
#pragma unroll
            for (int mi = 0; mi < 4; mi++)
                af[mi] = *reinterpret_cast<const bf16x8*>(&As[(wm + mi * 16 + l15) * 72 + kk + quad * 8]);
#pragma unroll
            for (int ni = 0; ni < 4; ni++)
                bfr[ni] = *reinterpret_cast<const bf16x8*>(&Bs[(wn + ni * 16 + l15) * 72 + kk + quad * 8]);
#pragma unroll
            for (int mi = 0; mi < 4; mi++)
#pragma unroll
                for (int ni = 0; ni < 4; ni++)
                    acc[mi][ni] = __builtin_amdgcn_mfma_f32_16x16x32_bf16(af[mi], bfr[ni], acc[mi][ni], 0, 0, 0);
        }
        __syncthreads();
    }

    // Phase B: gelu -> f16 -> LDS h1s[col][node] (overlays As/Bs; safe after barrier)
    bhalf* h1s = smem;                           // [128][136] (f16 bits)
#pragma unroll
    for (int mi = 0; mi < 4; mi++) {
        int node0 = wm + mi * 16 + quad * 4;     // local node (row)
#pragma unroll
        for (int ni = 0; ni < 4; ni++) {
            int col = wn + ni * 16 + l15;        // local h-col
            float bv = bias[bn + col];
            u16x4 o;
#pragma unroll
            for (int r = 0; r < 4; r++) {
                float v = acc[mi][ni][r] + bv;
                v = 0.5f * v * (1.0f + erff(v * 0.70710678118654752f));
                o[r] = __half_as_ushort(__float2half(v));
            }
            *reinterpret_cast<u16x4*>(&h1s[col * 136 + node0]) = o;
        }
    }
    __syncthreads();

    // Phase C: q-partial. A = wt16 (rows=g, contraction=node, in regs), B = h1s.
    f32x4 qacc[4][2] = {};
    const int c0 = wave * 32;                    // this wave's 32-col slice
#pragma unroll
    for (int ki = 0; ki < 4; ki++) {
        f16x8 bfr2[2];
#pragma unroll
        for (int ct = 0; ct < 2; ct++)
            bfr2[ct] = *reinterpret_cast<const f16x8*>(&h1s[(c0 + ct * 16 + l15) * 136 + ki * 32 + quad * 8]);
#pragma unroll
        for (int gt = 0; gt < 4; gt++)
#pragma unroll
            for (int ct = 0; ct < 2; ct++)
                qacc[gt][ct] = __builtin_amdgcn_mfma_f32_16x16x32_f16(wreg[ki][gt], bfr2[ct], qacc[gt][ct], 0, 0, 0);
    }
    // store: qpart[blk][g][col]; C layout: row(g)=gt*16+quad*4+r, col=c0+ct*16+l15
    float* qp = &qpart[(size_t)blockIdx.x * NG * 128];
#pragma unroll
    for (int gt = 0; gt < 4; gt++) {
#pragma unroll
        for (int ct = 0; ct < 2; ct++) {
            int col = c0 + ct * 16 + l15;
#pragma unroll
            for (int r = 0; r < 4; r++)
                qp[(gt * 16 + quad * 4 + r) * 128 + col] = qacc[gt][ct][r];
        }
    }
}

// ---------------- qpart reduce at full chip BW: qg[g][k] = sum_blk qpart ----------------

__global__ __launch_bounds__(256)
void qreduce_kernel(const float* __restrict__ qpart, float* __restrict__ qg) {
    __shared__ float red[256];
    int g = blockIdx.x >> 2;
    int chunk = blockIdx.x & 3;
    int half = chunk >> 1;
    int col128 = (chunk & 1) * 64 + (threadIdx.x & 63);
    int mi = threadIdx.x >> 6;
    float s = 0.0f;
    for (int m = mi; m < GEMM_MB; m += 4)
        s += qpart[(size_t)(m * 2 + half) * NG * 128 + (size_t)g * 128 + col128];
    red[threadIdx.x] = s;
    __syncthreads();
    if (mi == 0) {
        int kc = threadIdx.x;
        qg[(size_t)g * FH + half * 128 + col128] =
            red[kc] + red[64 + kc] + red[128 + kc] + red[192 + kc];
    }
}

// ---------------- fused head: pooled = (qg@W2)/cnt + b2 ; out = pooled@Wfc + bfc ----------------

__global__ __launch_bounds__(256)
void p2fc_kernel(const float* __restrict__ qg, const float* __restrict__ W2,
                 const float* __restrict__ b2, const int* __restrict__ batch,
                 const float* __restrict__ Wfc, const float* __restrict__ bfc,
                 float* __restrict__ out) {
    __shared__ float qgl[FH];
    __shared__ float ps[FH];
    int g = blockIdx.x;
    int t = threadIdx.x;
    qgl[t] = qg[(size_t)g * FH + t];
    int lo = 0, hi = NNODES;
    while (lo < hi) { int m = (lo + hi) >> 1; if (batch[m] < g) lo = m + 1; else hi = m; }
    int a = lo;
    lo = 0; hi = NNODES;
    while (lo < hi) { int m = (lo + hi) >> 1; if (batch[m] < g + 1) lo = m + 1; else hi = m; }
    float inv = 1.0f / fmaxf((float)(lo - a), 1.0f);
    __syncthreads();
    float acc = 0.0f;
    for (int k = 0; k < FH; k++)
        acc += qgl[k] * W2[k * FH + t];
    ps[t] = acc * inv + b2[t];
    __syncthreads();
    if (t < NC) {
        float a2 = 0.0f;
        for (int cc = 0; cc < FH; cc++)
            a2 += ps[cc] * Wfc[cc * NC + t];
        out[g * NC + t] = a2 + bfc[t];
    }
}

// ---------------- launch ----------------

extern "C" void kernel_launch(void* const* d_in, const int* in_sizes, int n_in,
                              void* d_out, int out_size, void* d_ws, size_t ws_size,
                              hipStream_t stream) {
    const float* x    = (const float*)d_in[0];
    const int*   ei   = (const int*)d_in[1];
    const int*   batch= (const int*)d_in[2];
    const float* W1   = (const float*)d_in[3];
    const float* b1   = (const float*)d_in[4];
    const float* W2   = (const float*)d_in[5];
    const float* b2   = (const float*)d_in[6];
    const float* Wfc  = (const float*)d_in[7];
    const float* bfc  = (const float*)d_in[8];
    float* out = (float*)d_out;

    const int* src = ei;
    const int* dst = ei + NEDGES;

    // workspace (~66 MB):
    bhalf* xb        = (bhalf*)d_ws;                       // [N,128] bf16 (12.8 MB)
    bhalf* zb        = xb + (size_t)NNODES * FIN;          // [N,128] bf16 (12.8 MB)
    unsigned int* edata  = (unsigned int*)(zb + (size_t)NNODES * FIN);  // [E] {f16 dinv_d | src} (3.2 MB)
    unsigned int* binned = edata + NEDGES;                 // [NBUCK*BCAP] u32 (4.0 MB)
    int*   row_start = (int*)(binned + (size_t)NBUCK * BCAP);  // [N+256]
    int*   bcur      = row_start + NNODES + 256;           // [256] (memset to 0)
    float* dinv      = (float*)(bcur + 256);               // [N+256]
    bhalf* w1t       = (bhalf*)(dinv + NNODES + 256);      // [256,128] bf16
    unsigned short* wt16 = (unsigned short*)(w1t + 256 * FIN);  // [64,NP] f16 (6.4 MB)
    float* qg        = (float*)(wt16 + (size_t)NG * NP);   // [64,256] f32 (64 KB)
    float* qpart     = qg + (size_t)NG * FH;               // [782,64,128] f32 (25.7 MB)

    (void)hipMemsetAsync(bcur, 0, NBUCK * 4, stream);

    // ---- CSR build + norms + staging (bin range overlaps splitx range) ----
    k1_kernel<<<K1_BLOCKS, 512, 0, stream>>>(src, dst, bcur, binned, x, xb, W1, w1t);
    place_kernel<<<NBUCK, 512, 0, stream>>>(binned, bcur, row_start, dinv, edata);

    // conv1 aggregate: z = bf16(Ahat*x)
    gather128_kernel<<<(NNODES + 3) / 4, 256, 0, stream>>>(xb, edata, row_start, dinv,
                                                           zb, NNODES);
    // pooling-weight matrix straight to f16 from CSR
    wt_build_kernel<<<NG * 4, 512, 0, stream>>>(edata, row_start, batch, dinv, wt16);

    // fused: h1 = gelu(z@W1+b1) (LDS-only) ; qpart[blk] = wt_blk @ h1_blk
    gemmq_kernel<<<GEMM_BLKS, 256, 0, stream>>>(zb, w1t, b1, wt16, qpart, NNODES);

    // reduce qpart at full BW, then tiny head
    qreduce_kernel<<<NG * 4, 256, 0, stream>>>(qpart, qg);
    p2fc_kernel<<<NG, FH, 0, stream>>>(qg, W2, b2, batch, Wfc, bfc, out);
}